// Round 14
// baseline (148.222 us; speedup 1.0000x reference)
//
#include <hip/hip_runtime.h>
#include <hip/hip_fp16.h>

// Tiny ViT forward, B=8192, fp32 compute. R6 structure (best: 97.7us):
// wave-per-IMAGE-PAIR packed in fx2 halves, per-wave LDS K/V (broadcast
// reads, zero barriers), s_load weights, one-pass softmax (no max sub).
// R14 = R13 with the cvt_pkrtz type fixed (__fp16 vector, not _Float16).
// K/V in LDS as packed FP16 (A,B) pairs. Attention reads 4
// ds_read_b128/s-iter (was 8); f16 operands consumed via the
// float(h16)*f32+acc pattern LLVM folds into v_fma_mix_f32 (op_sel f16
// operand, ZERO unpack instructions -- fixes R12's dependent-unpack
// regression). Pack side: one v_cvt_pkrtz_f16_f32 per pair.

typedef float fx2 __attribute__((ext_vector_type(2)));
typedef __fp16 hv2 __attribute__((ext_vector_type(2)));

#define T_TOK    50
#define WAVES_PB 4
#define THREADS  (WAVES_PB * 64)
#define KVSTRIDE 20                  // u32 per token: 16 data + 4 pad
#define SCALE    0.35355339059327373f   // 8^-0.5

#if __has_builtin(__builtin_amdgcn_exp2f)
  #define FASTEXP(x) __builtin_amdgcn_exp2f(x)
  #define QSCALE (SCALE * 1.4426950408889634f)   // fold log2(e) into q
#else
  #define FASTEXP(x) __expf(x)
  #define QSCALE SCALE
#endif

__device__ __forceinline__ fx2 bc(float s) { return (fx2){s, s}; }
__device__ __forceinline__ fx2 fmax2(fx2 a, fx2 b) {
    return (fx2){fmaxf(a.x, b.x), fmaxf(a.y, b.y)};
}
// pack fx2 (imgA,imgB) -> u32 of 2 fp16 (one v_cvt_pkrtz_f16_f32)
__device__ __forceinline__ unsigned pkh(fx2 v) {
    hv2 p = __builtin_amdgcn_cvt_pkrtz(v.x, v.y);
    return __builtin_bit_cast(unsigned, p);
}
// f16 lane extracts -- fold into v_fma_mix at the consumer
__device__ __forceinline__ float lof(unsigned u) {
    hv2 p = __builtin_bit_cast(hv2, u);
    return (float)p.x;
}
__device__ __forceinline__ float hif(unsigned u) {
    hv2 p = __builtin_bit_cast(hv2, u);
    return (float)p.y;
}

__global__ __launch_bounds__(THREADS) void vit_fwd(
    const float* __restrict__ images, const float* __restrict__ cls,
    const float* __restrict__ linW,
    const float* __restrict__ g1,  const float* __restrict__ be1,
    const float* __restrict__ Wq,  const float* __restrict__ Wk,
    const float* __restrict__ Wv,  const float* __restrict__ Pw,
    const float* __restrict__ Pb,  const float* __restrict__ g2,
    const float* __restrict__ be2, const float* __restrict__ W1,
    const float* __restrict__ bb1, const float* __restrict__ W2,
    const float* __restrict__ bb2, const float* __restrict__ mlpW,
    const float* __restrict__ mlpb,
    float* __restrict__ out, int B)
{
    __shared__ unsigned kv[WAVES_PB * T_TOK * KVSTRIDE];   // 16000 B

    const int lane = threadIdx.x & 63;
    const int wid  = threadIdx.x >> 6;
    const int pair = blockIdx.x * WAVES_PB + wid;   // wave-uniform
    const int gA   = pair * 2;
    if (gA >= B) return;
    const bool hasB = (gA + 1) < B;
    const int gB   = hasB ? gA + 1 : gA;
    const int t    = (lane < T_TOK) ? lane : (T_TOK - 1);
    unsigned* __restrict__ kvw = kv + wid * (T_TOK * KVSTRIDE);

    // ---- patch embed + positional (pos depends only on t: shared) ----
    fx2 x[8];
    {
        const float FR[4] = {1.f, 0.1f, 0.01f, 0.001f};
        float pos[8];
        #pragma unroll
        for (int j = 0; j < 8; ++j) {
            float arg = (float)t * FR[j >> 1];
            pos[j] = (j & 1) ? __cosf(arg) : __sinf(arg);
        }
        if (t == 0) {
            #pragma unroll
            for (int e = 0; e < 8; ++e) x[e] = bc(cls[e] + pos[e]);
        } else {
            const int p = t - 1, pr = p / 7, pc = p - pr * 7;
            const size_t off = (size_t)pr * 112 + pc * 4;
            const float* ibA = images + (size_t)gA * 784 + off;
            const float* ibB = images + (size_t)gB * 784 + off;
            fx2 pf[16];
            #pragma unroll
            for (int r = 0; r < 4; ++r) {
                float4 ua = *reinterpret_cast<const float4*>(ibA + r * 28);
                float4 ub = *reinterpret_cast<const float4*>(ibB + r * 28);
                pf[r*4+0] = (fx2){ua.x, ub.x}; pf[r*4+1] = (fx2){ua.y, ub.y};
                pf[r*4+2] = (fx2){ua.z, ub.z}; pf[r*4+3] = (fx2){ua.w, ub.w};
            }
            #pragma unroll
            for (int e = 0; e < 8; ++e) {
                fx2 a = bc(pos[e]);
                #pragma unroll
                for (int i = 0; i < 16; ++i) a += pf[i] * bc(linW[e*16 + i]);
                x[e] = a;
            }
        }
    }

    #pragma unroll 1
    for (int blk = 0; blk < 4; ++blk) {
        const int w8 = blk * 8, w64 = blk * 64, w256 = blk * 256, w32 = blk * 32;

        // ---- LN1 ----
        fx2 h[8];
        {
            fx2 mu = x[0];
            #pragma unroll
            for (int d = 1; d < 8; ++d) mu += x[d];
            mu *= bc(0.125f);
            fx2 var = bc(0.f);
            #pragma unroll
            for (int d = 0; d < 8; ++d) { fx2 dd = x[d] - mu; var += dd * dd; }
            var = var * bc(0.125f) + bc(1e-5f);
            fx2 rs = {rsqrtf(var.x), rsqrtf(var.y)};
            #pragma unroll
            for (int d = 0; d < 8; ++d)
                h[d] = (x[d] - mu) * rs * bc(g1[w8 + d]) + bc(be1[w8 + d]);
        }

        // ---- q,k,v: packed pk_fma chains (SGPR-broadcast weights) ----
        fx2 q[8], kk[8], vv[8];
        #pragma unroll
        for (int e = 0; e < 8; ++e) {
            fx2 aq = bc(0.f), ak = bc(0.f), av = bc(0.f);
            #pragma unroll
            for (int d = 0; d < 8; ++d) {
                aq += h[d] * bc(Wq[w64 + e*8 + d]);
                ak += h[d] * bc(Wk[w64 + e*8 + d]);
                av += h[d] * bc(Wv[w64 + e*8 + d]);
            }
            q[e] = aq * bc(QSCALE); kk[e] = ak; vv[e] = av;
        }
        {   // pack K then V as fp16 image-pairs: u32 = h16(A) | h16(B)<<16
            unsigned* kvp = kvw + t * KVSTRIDE;
            *reinterpret_cast<uint4*>(kvp +  0) =
                make_uint4(pkh(kk[0]), pkh(kk[1]), pkh(kk[2]), pkh(kk[3]));
            *reinterpret_cast<uint4*>(kvp +  4) =
                make_uint4(pkh(kk[4]), pkh(kk[5]), pkh(kk[6]), pkh(kk[7]));
            *reinterpret_cast<uint4*>(kvp +  8) =
                make_uint4(pkh(vv[0]), pkh(vv[1]), pkh(vv[2]), pkh(vv[3]));
            *reinterpret_cast<uint4*>(kvp + 12) =
                make_uint4(pkh(vv[4]), pkh(vv[5]), pkh(vv[6]), pkh(vv[7]));
        }

        // ---- attention: 4 broadcast b128 reads/s; v_fma_mix consumes f16 ----
        const float qA0=q[0].x,qA1=q[1].x,qA2=q[2].x,qA3=q[3].x;
        const float qA4=q[4].x,qA5=q[5].x,qA6=q[6].x,qA7=q[7].x;
        const float qB0=q[0].y,qB1=q[1].y,qB2=q[2].y,qB3=q[3].y;
        const float qB4=q[4].y,qB5=q[5].y,qB6=q[6].y,qB7=q[7].y;
        float lA0=0.f, lA1=0.f, lB0=0.f, lB1=0.f;
        float accA[8], accB[8];
        #pragma unroll
        for (int d = 0; d < 8; ++d) { accA[d] = 0.f; accB[d] = 0.f; }
        #pragma unroll 2
        for (int s = 0; s < T_TOK; ++s) {
            const unsigned* sp = kvw + s * KVSTRIDE;
            uint4 kw0 = *reinterpret_cast<const uint4*>(sp + 0);
            uint4 kw1 = *reinterpret_cast<const uint4*>(sp + 4);
            float dA0 = qA0*lof(kw0.x) + qA1*lof(kw0.y) + qA2*lof(kw0.z) + qA3*lof(kw0.w);
            float dA1 = qA4*lof(kw1.x) + qA5*lof(kw1.y) + qA6*lof(kw1.z) + qA7*lof(kw1.w);
            float dB0 = qB0*hif(kw0.x) + qB1*hif(kw0.y) + qB2*hif(kw0.z) + qB3*hif(kw0.w);
            float dB1 = qB4*hif(kw1.x) + qB5*hif(kw1.y) + qB6*hif(kw1.z) + qB7*hif(kw1.w);
            float pA0 = FASTEXP(dA0), pA1 = FASTEXP(dA1);
            float pB0 = FASTEXP(dB0), pB1 = FASTEXP(dB1);
            lA0 += pA0; lA1 += pA1; lB0 += pB0; lB1 += pB1;
            uint4 vw0 = *reinterpret_cast<const uint4*>(sp +  8);
            uint4 vw1 = *reinterpret_cast<const uint4*>(sp + 12);
            accA[0] = fmaf(pA0, lof(vw0.x), accA[0]);
            accA[1] = fmaf(pA0, lof(vw0.y), accA[1]);
            accA[2] = fmaf(pA0, lof(vw0.z), accA[2]);
            accA[3] = fmaf(pA0, lof(vw0.w), accA[3]);
            accA[4] = fmaf(pA1, lof(vw1.x), accA[4]);
            accA[5] = fmaf(pA1, lof(vw1.y), accA[5]);
            accA[6] = fmaf(pA1, lof(vw1.z), accA[6]);
            accA[7] = fmaf(pA1, lof(vw1.w), accA[7]);
            accB[0] = fmaf(pB0, hif(vw0.x), accB[0]);
            accB[1] = fmaf(pB0, hif(vw0.y), accB[1]);
            accB[2] = fmaf(pB0, hif(vw0.z), accB[2]);
            accB[3] = fmaf(pB0, hif(vw0.w), accB[3]);
            accB[4] = fmaf(pB1, hif(vw1.x), accB[4]);
            accB[5] = fmaf(pB1, hif(vw1.y), accB[5]);
            accB[6] = fmaf(pB1, hif(vw1.z), accB[6]);
            accB[7] = fmaf(pB1, hif(vw1.w), accB[7]);
        }
        fx2 o[8];
        {
            const float rA0 = 1.f / lA0, rA1 = 1.f / lA1;
            const float rB0 = 1.f / lB0, rB1 = 1.f / lB1;
            #pragma unroll
            for (int d = 0; d < 4; ++d) {
                o[d]   = (fx2){accA[d]   * rA0, accB[d]   * rB0};
                o[d+4] = (fx2){accA[d+4] * rA1, accB[d+4] * rB1};
            }
        }

        // ---- proj + residual ----
        fx2 xn[8];
        #pragma unroll
        for (int e = 0; e < 8; ++e) {
            fx2 a = bc(Pb[w8 + e]);
            #pragma unroll
            for (int d = 0; d < 8; ++d) a += o[d] * bc(Pw[w64 + e*8 + d]);
            xn[e] = x[e] + a;
        }

        // ---- LN2 ----
        fx2 h2v[8];
        {
            fx2 mu = xn[0];
            #pragma unroll
            for (int d = 1; d < 8; ++d) mu += xn[d];
            mu *= bc(0.125f);
            fx2 var = bc(0.f);
            #pragma unroll
            for (int d = 0; d < 8; ++d) { fx2 dd = xn[d] - mu; var += dd * dd; }
            var = var * bc(0.125f) + bc(1e-5f);
            fx2 rs = {rsqrtf(var.x), rsqrtf(var.y)};
            #pragma unroll
            for (int d = 0; d < 8; ++d)
                h2v[d] = (xn[d] - mu) * rs * bc(g2[w8 + d]) + bc(be2[w8 + d]);
        }

        // ---- FF ----
        {
            fx2 acc2[8];
            #pragma unroll
            for (int d = 0; d < 8; ++d) acc2[d] = bc(0.f);
            #pragma unroll 4
            for (int f = 0; f < 32; ++f) {
                fx2 a = bc(bb1[w32 + f]);
                #pragma unroll
                for (int d = 0; d < 8; ++d) a += h2v[d] * bc(W1[w256 + f*8 + d]);
                a = fmax2(a, bc(0.f));
                #pragma unroll
                for (int d = 0; d < 8; ++d) acc2[d] += a * bc(W2[w256 + d*32 + f]);
            }
            #pragma unroll
            for (int d = 0; d < 8; ++d)
                x[d] = xn[d] + acc2[d] + bc(bb2[w8 + d]);
        }
    }

    // ---- classification head: lane 0 (token 0), both images ----
    if (lane == 0) {
        fx2 lg[10]; fx2 mx = bc(-1e30f);
        #pragma unroll
        for (int c = 0; c < 10; ++c) {
            fx2 a = bc(mlpb[c]);
            #pragma unroll
            for (int d = 0; d < 8; ++d) a += x[d] * bc(mlpW[c*8 + d]);
            lg[c] = a; mx = fmax2(mx, a);
        }
        fx2 ssum = bc(0.f);
        #pragma unroll
        for (int c = 0; c < 10; ++c) {
            fx2 e = lg[c] - mx;
            lg[c] = (fx2){__expf(e.x), __expf(e.y)};
            ssum += lg[c];
        }
        const float rA = 1.f / ssum.x, rB = 1.f / ssum.y;
        #pragma unroll
        for (int c = 0; c < 10; ++c) {
            out[(size_t)gA*10 + c] = lg[c].x * rA;
            if (hasB) out[(size_t)gB*10 + c] = lg[c].y * rB;
        }
    }
}

extern "C" void kernel_launch(void* const* d_in, const int* in_sizes, int n_in,
                              void* d_out, int out_size, void* d_ws, size_t ws_size,
                              hipStream_t stream) {
    const int B = in_sizes[0] / 784;
    const int pairs = (B + 1) / 2;
    const int nblk = (pairs + WAVES_PB - 1) / WAVES_PB;
    vit_fwd<<<nblk, THREADS, 0, stream>>>(
        (const float*)d_in[0],  (const float*)d_in[1],  (const float*)d_in[2],
        (const float*)d_in[3],  (const float*)d_in[4],  (const float*)d_in[5],
        (const float*)d_in[6],  (const float*)d_in[7],  (const float*)d_in[8],
        (const float*)d_in[9],  (const float*)d_in[10], (const float*)d_in[11],
        (const float*)d_in[12], (const float*)d_in[13], (const float*)d_in[14],
        (const float*)d_in[15], (const float*)d_in[16], (const float*)d_in[17],
        (float*)d_out, B);
}